// Round 4
// baseline (432.324 us; speedup 1.0000x reference)
//
#include <hip/hip_runtime.h>
#include <hip/hip_bf16.h>

// COO SpMM scatter-add: y[row[i]] += value[i] * x[col[i]], D=64.
// One 64-lane wave per nonzero; lane d handles feature column d.
//   - row/col/value loads are wave-uniform broadcasts
//   - x-row read is one coalesced 256B segment
//   - output: 64 coalesced f32 atomicAdds per nnz

#define D 64

__global__ __launch_bounds__(256) void spmm_scatter_kernel(
    const float* __restrict__ x,
    const int* __restrict__ row,
    const int* __restrict__ col,
    const float* __restrict__ value,
    float* __restrict__ y,
    int nnz) {
  int gid  = blockIdx.x * blockDim.x + threadIdx.x;
  int lane = gid & (D - 1);   // feature index 0..63
  int i    = gid >> 6;        // nonzero index
  if (i >= nnz) return;

  int   r = row[i];
  int   c = col[i];
  float v = value[i];

  float xv = x[(size_t)c * D + lane];
  atomicAdd(&y[(size_t)r * D + lane], v * xv);
}

extern "C" void kernel_launch(void* const* d_in, const int* in_sizes, int n_in,
                              void* d_out, int out_size, void* d_ws, size_t ws_size,
                              hipStream_t stream) {
  const float* x     = (const float*)d_in[0];
  const int*   row   = (const int*)d_in[1];
  const int*   col   = (const int*)d_in[2];
  const float* value = (const float*)d_in[3];
  // d_in[4] = size scalar (N); out_size == N * D anyway.

  float* y  = (float*)d_out;
  int    nnz = in_sizes[1];

  // d_out is poisoned with 0xAA before every timed launch — zero it.
  hipMemsetAsync(y, 0, (size_t)out_size * sizeof(float), stream);

  long long total_threads = (long long)nnz * D;
  int block = 256;
  int grid  = (int)((total_threads + block - 1) / block);
  spmm_scatter_kernel<<<grid, block, 0, stream>>>(x, row, col, value, y, nnz);
}